// Round 8
// baseline (650.138 us; speedup 1.0000x reference)
//
#include <hip/hip_runtime.h>

// ---------------------------------------------------------------------------
// GCNnet: 3x GCNConv (40->40->80->128) + global max pool + MLP(128->512->2) + softmax
// N=100000 nodes, E=1600000 edges, G=512 graphs.
// Round 7: GEMM register tile 2 nodes -> 8 nodes per thread.
//   FMA : ds_read_b128 ratio 8:1 -> 32:1 (R6 profile: LDS reads ate ~43% of
//   issue slots, VALUBusy 49%). X loads become wave-broadcast (address depends
//   only on p-slot); W LDS reads 4x fewer. Bank conflicts measured negligible
//   (1.2M cyc ~ 2.6%) — not chased. Pool fusion / bf16 gather unchanged.
// ---------------------------------------------------------------------------

static inline int cdiv(long a, int b) { return (int)((a + b - 1) / b); }
static inline size_t align256(size_t x) { return (x + 255) & ~(size_t)255; }

#define FXSCALE 16777216.0f           // 2^24
#define FXMASK  ((1ULL << 40) - 1)
#define SCHUNK  1024                  // elements per scan block

__device__ __forceinline__ float bf2f(unsigned short u) {
    return __uint_as_float(((unsigned int)u) << 16);
}
__device__ __forceinline__ unsigned short f2bf(float f) {   // round-nearest-even
    unsigned int u = __float_as_uint(f);
    return (unsigned short)((u + 0x7FFFu + ((u >> 16) & 1u)) >> 16);
}

// one u64 atomic per edge: high 24 bits count, low 40 bits fixed-point weight sum.
// old >> 40 = this edge's rank within its destination segment.
__global__ void deg_count_kernel(const int* __restrict__ col, const float* __restrict__ w,
                                 unsigned long long* __restrict__ packed,
                                 int* __restrict__ rank, int E) {
    int e = blockIdx.x * blockDim.x + threadIdx.x;
    if (e >= E) return;
    int c = col[e];
    unsigned long long fx = (unsigned long long)llrintf(w[e] * FXSCALE);
    unsigned long long old = atomicAdd(&packed[c], (1ULL << 40) | fx);
    rank[e] = (int)(old >> 40);
}

// scan phase A: per-block count sums + dinv (256 thr x 4 elems = 1024/block)
__global__ void scanA_kernel(const unsigned long long* __restrict__ packed,
                             float* __restrict__ dinv, int* __restrict__ blockSums, int N) {
    __shared__ int wred[4];
    int tid = threadIdx.x, lane = tid & 63, wid = tid >> 6;
    int i0 = blockIdx.x * SCHUNK + tid * 4;
    int s = 0;
#pragma unroll
    for (int k = 0; k < 4; ++k) {
        int i = i0 + k;
        if (i < N) {
            unsigned long long p = packed[i];
            s += (int)(p >> 40);
            float deg = (float)(p & FXMASK) * (1.0f / FXSCALE);
            dinv[i] = rsqrtf(deg + 1.0f);
        }
    }
#pragma unroll
    for (int off = 32; off > 0; off >>= 1) s += __shfl_down(s, off, 64);
    if (lane == 0) wred[wid] = s;
    __syncthreads();
    if (tid == 0) blockSums[blockIdx.x] = wred[0] + wred[1] + wred[2] + wred[3];
}

// scan phase B: one block, exclusive scan of blockSums[nb] (nb <= 1024);
// writes total into offs[N].
__global__ void scanB_kernel(int* __restrict__ blockSums, int* __restrict__ offs,
                             int nb, int N) {
    __shared__ int wsum[16];
    int tid = threadIdx.x, lane = tid & 63, wid = tid >> 6;
    int v = (tid < nb) ? blockSums[tid] : 0;
    int incl = v;
#pragma unroll
    for (int off = 1; off < 64; off <<= 1) {
        int t = __shfl_up(incl, off, 64);
        if (lane >= off) incl += t;
    }
    if (lane == 63) wsum[wid] = incl;
    __syncthreads();
    if (wid == 0 && lane < 16) {
        int w = wsum[lane];
        int ic = w;
#pragma unroll
        for (int off = 1; off < 16; off <<= 1) {
            int t = __shfl_up(ic, off, 64);
            if (lane >= off) ic += t;
        }
        wsum[lane] = ic - w;   // exclusive
    }
    __syncthreads();
    if (tid < nb) blockSums[tid] = wsum[wid] + incl - v;   // exclusive prefix
    if (tid == 1023) offs[N] = wsum[15] + incl;            // grand total
}

// scan phase C: local exclusive scan + block offset -> offs
__global__ void scanC_kernel(const unsigned long long* __restrict__ packed,
                             const int* __restrict__ blockSums,
                             int* __restrict__ offs, int N) {
    __shared__ int wsum[4];
    int tid = threadIdx.x, lane = tid & 63, wid = tid >> 6;
    int i0 = blockIdx.x * SCHUNK + tid * 4;
    int v0 = 0, v1 = 0, v2 = 0, v3 = 0;
    if (i0 + 0 < N) v0 = (int)(packed[i0 + 0] >> 40);
    if (i0 + 1 < N) v1 = (int)(packed[i0 + 1] >> 40);
    if (i0 + 2 < N) v2 = (int)(packed[i0 + 2] >> 40);
    if (i0 + 3 < N) v3 = (int)(packed[i0 + 3] >> 40);
    int sum = v0 + v1 + v2 + v3;
    int incl = sum;
#pragma unroll
    for (int off = 1; off < 64; off <<= 1) {
        int t = __shfl_up(incl, off, 64);
        if (lane >= off) incl += t;
    }
    if (lane == 63) wsum[wid] = incl;
    __syncthreads();
    if (tid == 0) {
        int c = 0;
#pragma unroll
        for (int k = 0; k < 4; ++k) { int t = wsum[k]; wsum[k] = c; c += t; }
    }
    __syncthreads();
    int pre = blockSums[blockIdx.x] + wsum[wid] + (incl - sum);
    if (i0 + 0 < N) offs[i0 + 0] = pre;
    if (i0 + 1 < N) offs[i0 + 1] = pre + v0;
    if (i0 + 2 < N) offs[i0 + 2] = pre + v0 + v1;
    if (i0 + 3 < N) offs[i0 + 3] = pre + v0 + v1 + v2;
}

// CSR fill, atomic-free: pos = offs[col] + rank; perm = {row, norm bits} (8B store)
__global__ void fill_kernel(const int* __restrict__ row, const int* __restrict__ col,
                            const float* __restrict__ w, const int* __restrict__ rank,
                            const float* __restrict__ dinv, const int* __restrict__ offs,
                            int2* __restrict__ perm, int E) {
    int e = blockIdx.x * blockDim.x + threadIdx.x;
    if (e >= E) return;
    int r = row[e], c = col[e];
    int pos = offs[c] + rank[e];
    float nm = dinv[r] * w[e] * dinv[c];
    perm[pos] = make_int2(r, __float_as_int(nm));
}

// f32 -> bf16 bulk convert (n divisible by 4)
__global__ void f2bf_kernel(const float* __restrict__ in, ushort* __restrict__ out, int n4) {
    int i = blockIdx.x * blockDim.x + threadIdx.x;
    if (i >= n4) return;
    float4 v = ((const float4*)in)[i];
    ((ushort4*)out)[i] = make_ushort4(f2bf(v.x), f2bf(v.y), f2bf(v.z), f2bf(v.w));
}

// agg[d] = sum_{e: col=d} H[row_e]*norm_e + dinv[d]^2*H[d]   (H in bf16)
// thread = (node, 4 feats); 4-edge unroll -> 4 independent load chains
template<int F>
__global__ void gather_kernel(const int* __restrict__ offs, const int2* __restrict__ perm,
                              const ushort* __restrict__ H, const float* __restrict__ dinv,
                              float* __restrict__ agg, int N) {
    constexpr int TPN = F / 4;
    int idx = blockIdx.x * blockDim.x + threadIdx.x;
    int node = idx / TPN, q = idx % TPN;
    if (node >= N) return;
    int s = offs[node], e = offs[node + 1];
    float4 a0 = make_float4(0.f, 0.f, 0.f, 0.f);
    float4 a1 = make_float4(0.f, 0.f, 0.f, 0.f);
    int j = s;
    for (; j + 4 <= e; j += 4) {
        int2 p0 = perm[j + 0], p1 = perm[j + 1], p2 = perm[j + 2], p3 = perm[j + 3];
        float m0 = __int_as_float(p0.y), m1 = __int_as_float(p1.y);
        float m2 = __int_as_float(p2.y), m3 = __int_as_float(p3.y);
        ushort4 u0 = *(const ushort4*)(H + (long)p0.x * F + q * 4);
        ushort4 u1 = *(const ushort4*)(H + (long)p1.x * F + q * 4);
        ushort4 u2 = *(const ushort4*)(H + (long)p2.x * F + q * 4);
        ushort4 u3 = *(const ushort4*)(H + (long)p3.x * F + q * 4);
        a0.x += bf2f(u0.x) * m0; a0.y += bf2f(u0.y) * m0;
        a0.z += bf2f(u0.z) * m0; a0.w += bf2f(u0.w) * m0;
        a1.x += bf2f(u1.x) * m1; a1.y += bf2f(u1.y) * m1;
        a1.z += bf2f(u1.z) * m1; a1.w += bf2f(u1.w) * m1;
        a0.x += bf2f(u2.x) * m2; a0.y += bf2f(u2.y) * m2;
        a0.z += bf2f(u2.z) * m2; a0.w += bf2f(u2.w) * m2;
        a1.x += bf2f(u3.x) * m3; a1.y += bf2f(u3.y) * m3;
        a1.z += bf2f(u3.z) * m3; a1.w += bf2f(u3.w) * m3;
    }
    for (; j < e; ++j) {
        int2 p = perm[j];
        float nm = __int_as_float(p.y);
        ushort4 u = *(const ushort4*)(H + (long)p.x * F + q * 4);
        a0.x += bf2f(u.x) * nm; a0.y += bf2f(u.y) * nm;
        a0.z += bf2f(u.z) * nm; a0.w += bf2f(u.w) * nm;
    }
    float di = dinv[node], d2 = di * di;
    ushort4 su = *(const ushort4*)(H + (long)node * F + q * 4);
    float4 o = make_float4(a0.x + a1.x + d2 * bf2f(su.x), a0.y + a1.y + d2 * bf2f(su.y),
                           a0.z + a1.z + d2 * bf2f(su.z), a0.w + a1.w + d2 * bf2f(su.w));
    *(float4*)(agg + (long)node * F + q * 4) = o;
}

// out[N,FOUT] = relu(X[N,K] @ W[K,FOUT] + bias)
// thread = (NPT=8 nodes, 4 feats); W in LDS. Per W ds_read_b128: 32 FMAs.
// X loads are wave-broadcast (address depends only on p-slot).
// BF16OUT: store ushort4 bf16. FUSE_POOL: hierarchical max-pool (2-graph LDS
// window, zero-skipping flush; direct global atomics if rel >= 2).
template<int K, int FOUT, int BLK, bool FUSE_POOL, bool BF16OUT>
__global__ __launch_bounds__(BLK)
void gemm_kernel(const float* __restrict__ X, const float* __restrict__ W,
                 const float* __restrict__ bias, void* __restrict__ out,
                 const int* __restrict__ batch, unsigned int* __restrict__ g, int N) {
    constexpr int NPT = 8;                 // nodes per thread
    constexpr int TPQ = FOUT / 4;          // feature-group slots
    constexpr int PSLOTS = BLK / TPQ;      // node-groups per block
    constexpr int NPB = PSLOTS * NPT;      // nodes per block
    __shared__ float wsm[K * FOUT];
    __shared__ unsigned int gma[FUSE_POOL ? 2 * FOUT : 1];
    __shared__ int gfirst;
    for (int i = threadIdx.x; i < K * FOUT; i += BLK) wsm[i] = W[i];
    if (FUSE_POOL) {
        if (threadIdx.x == 0) gfirst = batch[min((int)(blockIdx.x * NPB), N - 1)];
        for (int i = threadIdx.x; i < 2 * FOUT; i += BLK) gma[i] = 0u;
    }
    __syncthreads();

    int q = threadIdx.x % TPQ, p = threadIdx.x / TPQ;
    long nbase = (long)blockIdx.x * NPB + (long)p * NPT;

    float4 acc[NPT];
#pragma unroll
    for (int t = 0; t < NPT; ++t) acc[t] = make_float4(0.f, 0.f, 0.f, 0.f);

    const float* wq = wsm + q * 4;
    for (int i = 0; i < K / 4; ++i) {
        float4 xv[NPT];
#pragma unroll
        for (int t = 0; t < NPT; ++t) {
            long n = nbase + t; if (n >= N) n = N - 1;    // clamp (masked at store)
            xv[t] = *(const float4*)(X + n * K + i * 4);
        }
#pragma unroll
        for (int j = 0; j < 4; ++j) {
            float4 wv = *(const float4*)(wq + (i * 4 + j) * FOUT);
#pragma unroll
            for (int t = 0; t < NPT; ++t) {
                float v = ((const float*)&xv[t])[j];
                acc[t].x += v * wv.x; acc[t].y += v * wv.y;
                acc[t].z += v * wv.z; acc[t].w += v * wv.w;
            }
        }
    }

    float4 bv = *(const float4*)(bias + q * 4);
#pragma unroll
    for (int t = 0; t < NPT; ++t) {
        acc[t].x = fmaxf(acc[t].x + bv.x, 0.f);
        acc[t].y = fmaxf(acc[t].y + bv.y, 0.f);
        acc[t].z = fmaxf(acc[t].z + bv.z, 0.f);
        acc[t].w = fmaxf(acc[t].w + bv.w, 0.f);
    }

    if (!FUSE_POOL) {
        if (BF16OUT) {
            ushort* ob = (ushort*)out;
#pragma unroll
            for (int t = 0; t < NPT; ++t) {
                long n = nbase + t;
                if (n < N)
                    *(ushort4*)(ob + n * FOUT + q * 4) =
                        make_ushort4(f2bf(acc[t].x), f2bf(acc[t].y),
                                     f2bf(acc[t].z), f2bf(acc[t].w));
            }
        } else {
            float* of = (float*)out;
#pragma unroll
            for (int t = 0; t < NPT; ++t) {
                long n = nbase + t;
                if (n < N) *(float4*)(of + n * FOUT + q * 4) = acc[t];
            }
        }
        return;
    }

    // ---- hierarchical pool ----
#pragma unroll
    for (int t = 0; t < NPT; ++t) {
        long n = nbase + t;
        if (n < N) {
            unsigned int bx = __float_as_uint(acc[t].x), by = __float_as_uint(acc[t].y);
            unsigned int bz = __float_as_uint(acc[t].z), bw = __float_as_uint(acc[t].w);
            int rel = batch[n] - gfirst;
            if (rel < 2) {
                unsigned int* d = gma + rel * FOUT + q * 4;
                atomicMax(d + 0, bx); atomicMax(d + 1, by);
                atomicMax(d + 2, bz); atomicMax(d + 3, bw);
            } else {
                unsigned int* d = g + (long)batch[n] * FOUT + q * 4;
                atomicMax(d + 0, bx); atomicMax(d + 1, by);
                atomicMax(d + 2, bz); atomicMax(d + 3, bw);
            }
        }
    }
    __syncthreads();
    for (int i = threadIdx.x; i < 2 * FOUT; i += BLK) {
        unsigned int v = gma[i];
        if (v) atomicMax(&g[(long)(gfirst + i / FOUT) * FOUT + (i % FOUT)], v);
    }
}

// one block per graph: relu(g@Wfc1+bfc1) @ Wfc2 + bfc2 -> softmax
__global__ void fc_kernel(const float* __restrict__ g, const float* __restrict__ Wfc1,
                          const float* __restrict__ bfc1, const float* __restrict__ Wfc2,
                          const float* __restrict__ bfc2, float* __restrict__ out) {
    __shared__ float gs[128];
    __shared__ float red0[256], red1[256];
    int b = blockIdx.x, tid = threadIdx.x;
    if (tid < 128) gs[tid] = g[b * 128 + tid];
    __syncthreads();
    float h0 = bfc1[tid], h1 = bfc1[tid + 256];
    for (int k = 0; k < 128; ++k) {
        float gv = gs[k];
        h0 += gv * Wfc1[k * 512 + tid];
        h1 += gv * Wfc1[k * 512 + tid + 256];
    }
    h0 = fmaxf(h0, 0.f); h1 = fmaxf(h1, 0.f);
    red0[tid] = h0 * Wfc2[tid * 2 + 0] + h1 * Wfc2[(tid + 256) * 2 + 0];
    red1[tid] = h0 * Wfc2[tid * 2 + 1] + h1 * Wfc2[(tid + 256) * 2 + 1];
    __syncthreads();
    for (int s = 128; s > 0; s >>= 1) {
        if (tid < s) { red0[tid] += red0[tid + s]; red1[tid] += red1[tid + s]; }
        __syncthreads();
    }
    if (tid == 0) {
        float L0 = red0[0] + bfc2[0], L1 = red1[0] + bfc2[1];
        float m = fmaxf(L0, L1);
        float e0 = expf(L0 - m), e1 = expf(L1 - m);
        float inv = 1.f / (e0 + e1);
        out[b * 2 + 0] = e0 * inv;
        out[b * 2 + 1] = e1 * inv;
    }
}

extern "C" void kernel_launch(void* const* d_in, const int* in_sizes, int n_in,
                              void* d_out, int out_size, void* d_ws, size_t ws_size,
                              hipStream_t stream) {
    const float* x     = (const float*)d_in[0];
    const int*   ei    = (const int*)d_in[1];
    const float* ew    = (const float*)d_in[2];
    const int*   batch = (const int*)d_in[3];
    const float* W1    = (const float*)d_in[4];
    const float* b1    = (const float*)d_in[5];
    const float* W2    = (const float*)d_in[6];
    const float* b2    = (const float*)d_in[7];
    const float* W3    = (const float*)d_in[8];
    const float* b3    = (const float*)d_in[9];
    const float* Wfc1  = (const float*)d_in[10];
    const float* bfc1  = (const float*)d_in[11];
    const float* Wfc2  = (const float*)d_in[12];
    const float* bfc2  = (const float*)d_in[13];

    const int N = in_sizes[3];      // 100000
    const int E = in_sizes[2];      // 1600000
    const int* row = ei;
    const int* col = ei + E;

    char* ws = (char*)d_ws;
    float* dinv   = (float*)ws;              ws += align256((size_t)N * 4);
    unsigned long long* packed = (unsigned long long*)ws; ws += align256((size_t)N * 8);
    int*   offs   = (int*)ws;                ws += align256((size_t)(N + 1) * 4);
    int*   bsums  = (int*)ws;                ws += align256((size_t)1024 * 4);
    int2*  perm   = (int2*)ws;               ws += align256((size_t)E * 8);
    float* bufA   = (float*)ws;              ws += align256((size_t)N * 128 * 4);  // agg f32
    ushort* bufH  = (ushort*)ws;             ws += align256((size_t)N * 128 * 2);  // H bf16
    ushort* xbf   = (ushort*)ws;             ws += align256((size_t)N * 40 * 2);   // x bf16
    float* g      = (float*)ws;              ws += align256((size_t)512 * 128 * 4);
    int*   rank   = (int*)bufA;   // rank[E] (6.4MB) aliases bufA — dead before gather1

    const int B = 256;
    const int nScanBlocks = cdiv(N, SCHUNK);   // 98 for N=100000 (<= 1024)

    // --- gcn_norm + CSR build ---
    hipMemsetAsync(packed, 0, (size_t)N * 8, stream);
    deg_count_kernel<<<cdiv(E, B), B, 0, stream>>>(col, ew, packed, rank, E);
    scanA_kernel<<<nScanBlocks, B, 0, stream>>>(packed, dinv, bsums, N);
    scanB_kernel<<<1, 1024, 0, stream>>>(bsums, offs, nScanBlocks, N);
    scanC_kernel<<<nScanBlocks, B, 0, stream>>>(packed, bsums, offs, N);
    fill_kernel<<<cdiv(E, B), B, 0, stream>>>(row, col, ew, rank, dinv, offs, perm, E);
    f2bf_kernel<<<cdiv((long)N * 10, B), B, 0, stream>>>(x, xbf, N * 10);

    // --- conv1: agg = A*x (40-wide bf16), H1 = relu(agg@W1 + b1) -> bufH (bf16) ---
    // gemm1: K=40 FOUT=40 BLK=320 -> TPQ=10, 32 p-slots, 256 nodes/block
    gather_kernel<40><<<cdiv((long)N * 10, B), B, 0, stream>>>(
        offs, perm, xbf, dinv, bufA, N);
    gemm_kernel<40, 40, 320, false, true><<<cdiv(N, 256), 320, 0, stream>>>(
        bufA, W1, b1, bufH, nullptr, nullptr, N);

    // --- conv2: agg = A*H1 (40-wide bf16), H2 = relu(agg@W2 + b2) -> bufH (bf16) ---
    // gemm2: K=40 FOUT=80 BLK=320 -> TPQ=20, 16 p-slots, 128 nodes/block
    gather_kernel<40><<<cdiv((long)N * 10, B), B, 0, stream>>>(
        offs, perm, bufH, dinv, bufA, N);
    gemm_kernel<40, 80, 320, false, true><<<cdiv(N, 128), 320, 0, stream>>>(
        bufA, W2, b2, bufH, nullptr, nullptr, N);

    // --- conv3: agg = A*H2 (80-wide bf16), pool(relu(agg@W3 + b3)) -> g ---
    // gemm3: K=80 FOUT=128 BLK=256 -> TPQ=32, 8 p-slots, 64 nodes/block
    gather_kernel<80><<<cdiv((long)N * 20, B), B, 0, stream>>>(
        offs, perm, bufH, dinv, bufA, N);
    hipMemsetAsync(g, 0, (size_t)512 * 128 * 4, stream);
    gemm_kernel<80, 128, 256, true, false><<<cdiv(N, 64), 256, 0, stream>>>(
        bufA, W3, b3, nullptr, batch, (unsigned int*)g, N);

    // --- MLP + softmax ---
    fc_kernel<<<512, 256, 0, stream>>>(g, Wfc1, bfc1, Wfc2, bfc2, (float*)d_out);
}

// Round 9
// 430.913 us; speedup vs baseline: 1.5087x; 1.5087x over previous
//
#include <hip/hip_runtime.h>

// ---------------------------------------------------------------------------
// GCNnet: 3x GCNConv (40->40->80->128) + global max pool + MLP(128->512->2) + softmax
// N=100000 nodes, E=1600000 edges, G=512 graphs.
// Round 8: revert R7's 8-node GEMM tile (441 MB hbm_bytes, 14x amplification:
// strided 16B reads thrashed L1, 8B stores defeated write-combining).
// Back to R6 structure with NPT=4 (was 2): FMA:ds_read 16:1, block node
// footprint 10-20KB (L1-resident), stores contiguous in 4-row groups.
// ---------------------------------------------------------------------------

static inline int cdiv(long a, int b) { return (int)((a + b - 1) / b); }
static inline size_t align256(size_t x) { return (x + 255) & ~(size_t)255; }

#define FXSCALE 16777216.0f           // 2^24
#define FXMASK  ((1ULL << 40) - 1)
#define SCHUNK  1024                  // elements per scan block

__device__ __forceinline__ float bf2f(unsigned short u) {
    return __uint_as_float(((unsigned int)u) << 16);
}
__device__ __forceinline__ unsigned short f2bf(float f) {   // round-nearest-even
    unsigned int u = __float_as_uint(f);
    return (unsigned short)((u + 0x7FFFu + ((u >> 16) & 1u)) >> 16);
}

// one u64 atomic per edge: high 24 bits count, low 40 bits fixed-point weight sum.
// old >> 40 = this edge's rank within its destination segment.
__global__ void deg_count_kernel(const int* __restrict__ col, const float* __restrict__ w,
                                 unsigned long long* __restrict__ packed,
                                 int* __restrict__ rank, int E) {
    int e = blockIdx.x * blockDim.x + threadIdx.x;
    if (e >= E) return;
    int c = col[e];
    unsigned long long fx = (unsigned long long)llrintf(w[e] * FXSCALE);
    unsigned long long old = atomicAdd(&packed[c], (1ULL << 40) | fx);
    rank[e] = (int)(old >> 40);
}

// scan phase A: per-block count sums + dinv (256 thr x 4 elems = 1024/block)
__global__ void scanA_kernel(const unsigned long long* __restrict__ packed,
                             float* __restrict__ dinv, int* __restrict__ blockSums, int N) {
    __shared__ int wred[4];
    int tid = threadIdx.x, lane = tid & 63, wid = tid >> 6;
    int i0 = blockIdx.x * SCHUNK + tid * 4;
    int s = 0;
#pragma unroll
    for (int k = 0; k < 4; ++k) {
        int i = i0 + k;
        if (i < N) {
            unsigned long long p = packed[i];
            s += (int)(p >> 40);
            float deg = (float)(p & FXMASK) * (1.0f / FXSCALE);
            dinv[i] = rsqrtf(deg + 1.0f);
        }
    }
#pragma unroll
    for (int off = 32; off > 0; off >>= 1) s += __shfl_down(s, off, 64);
    if (lane == 0) wred[wid] = s;
    __syncthreads();
    if (tid == 0) blockSums[blockIdx.x] = wred[0] + wred[1] + wred[2] + wred[3];
}

// scan phase B: one block, exclusive scan of blockSums[nb] (nb <= 1024);
// writes total into offs[N].
__global__ void scanB_kernel(int* __restrict__ blockSums, int* __restrict__ offs,
                             int nb, int N) {
    __shared__ int wsum[16];
    int tid = threadIdx.x, lane = tid & 63, wid = tid >> 6;
    int v = (tid < nb) ? blockSums[tid] : 0;
    int incl = v;
#pragma unroll
    for (int off = 1; off < 64; off <<= 1) {
        int t = __shfl_up(incl, off, 64);
        if (lane >= off) incl += t;
    }
    if (lane == 63) wsum[wid] = incl;
    __syncthreads();
    if (wid == 0 && lane < 16) {
        int w = wsum[lane];
        int ic = w;
#pragma unroll
        for (int off = 1; off < 16; off <<= 1) {
            int t = __shfl_up(ic, off, 64);
            if (lane >= off) ic += t;
        }
        wsum[lane] = ic - w;   // exclusive
    }
    __syncthreads();
    if (tid < nb) blockSums[tid] = wsum[wid] + incl - v;   // exclusive prefix
    if (tid == 1023) offs[N] = wsum[15] + incl;            // grand total
}

// scan phase C: local exclusive scan + block offset -> offs
__global__ void scanC_kernel(const unsigned long long* __restrict__ packed,
                             const int* __restrict__ blockSums,
                             int* __restrict__ offs, int N) {
    __shared__ int wsum[4];
    int tid = threadIdx.x, lane = tid & 63, wid = tid >> 6;
    int i0 = blockIdx.x * SCHUNK + tid * 4;
    int v0 = 0, v1 = 0, v2 = 0, v3 = 0;
    if (i0 + 0 < N) v0 = (int)(packed[i0 + 0] >> 40);
    if (i0 + 1 < N) v1 = (int)(packed[i0 + 1] >> 40);
    if (i0 + 2 < N) v2 = (int)(packed[i0 + 2] >> 40);
    if (i0 + 3 < N) v3 = (int)(packed[i0 + 3] >> 40);
    int sum = v0 + v1 + v2 + v3;
    int incl = sum;
#pragma unroll
    for (int off = 1; off < 64; off <<= 1) {
        int t = __shfl_up(incl, off, 64);
        if (lane >= off) incl += t;
    }
    if (lane == 63) wsum[wid] = incl;
    __syncthreads();
    if (tid == 0) {
        int c = 0;
#pragma unroll
        for (int k = 0; k < 4; ++k) { int t = wsum[k]; wsum[k] = c; c += t; }
    }
    __syncthreads();
    int pre = blockSums[blockIdx.x] + wsum[wid] + (incl - sum);
    if (i0 + 0 < N) offs[i0 + 0] = pre;
    if (i0 + 1 < N) offs[i0 + 1] = pre + v0;
    if (i0 + 2 < N) offs[i0 + 2] = pre + v0 + v1;
    if (i0 + 3 < N) offs[i0 + 3] = pre + v0 + v1 + v2;
}

// CSR fill, atomic-free: pos = offs[col] + rank; perm = {row, norm bits} (8B store)
__global__ void fill_kernel(const int* __restrict__ row, const int* __restrict__ col,
                            const float* __restrict__ w, const int* __restrict__ rank,
                            const float* __restrict__ dinv, const int* __restrict__ offs,
                            int2* __restrict__ perm, int E) {
    int e = blockIdx.x * blockDim.x + threadIdx.x;
    if (e >= E) return;
    int r = row[e], c = col[e];
    int pos = offs[c] + rank[e];
    float nm = dinv[r] * w[e] * dinv[c];
    perm[pos] = make_int2(r, __float_as_int(nm));
}

// f32 -> bf16 bulk convert (n divisible by 4)
__global__ void f2bf_kernel(const float* __restrict__ in, ushort* __restrict__ out, int n4) {
    int i = blockIdx.x * blockDim.x + threadIdx.x;
    if (i >= n4) return;
    float4 v = ((const float4*)in)[i];
    ((ushort4*)out)[i] = make_ushort4(f2bf(v.x), f2bf(v.y), f2bf(v.z), f2bf(v.w));
}

// agg[d] = sum_{e: col=d} H[row_e]*norm_e + dinv[d]^2*H[d]   (H in bf16)
// thread = (node, 4 feats); 4-edge unroll -> 4 independent load chains
template<int F>
__global__ void gather_kernel(const int* __restrict__ offs, const int2* __restrict__ perm,
                              const ushort* __restrict__ H, const float* __restrict__ dinv,
                              float* __restrict__ agg, int N) {
    constexpr int TPN = F / 4;
    int idx = blockIdx.x * blockDim.x + threadIdx.x;
    int node = idx / TPN, q = idx % TPN;
    if (node >= N) return;
    int s = offs[node], e = offs[node + 1];
    float4 a0 = make_float4(0.f, 0.f, 0.f, 0.f);
    float4 a1 = make_float4(0.f, 0.f, 0.f, 0.f);
    int j = s;
    for (; j + 4 <= e; j += 4) {
        int2 p0 = perm[j + 0], p1 = perm[j + 1], p2 = perm[j + 2], p3 = perm[j + 3];
        float m0 = __int_as_float(p0.y), m1 = __int_as_float(p1.y);
        float m2 = __int_as_float(p2.y), m3 = __int_as_float(p3.y);
        ushort4 u0 = *(const ushort4*)(H + (long)p0.x * F + q * 4);
        ushort4 u1 = *(const ushort4*)(H + (long)p1.x * F + q * 4);
        ushort4 u2 = *(const ushort4*)(H + (long)p2.x * F + q * 4);
        ushort4 u3 = *(const ushort4*)(H + (long)p3.x * F + q * 4);
        a0.x += bf2f(u0.x) * m0; a0.y += bf2f(u0.y) * m0;
        a0.z += bf2f(u0.z) * m0; a0.w += bf2f(u0.w) * m0;
        a1.x += bf2f(u1.x) * m1; a1.y += bf2f(u1.y) * m1;
        a1.z += bf2f(u1.z) * m1; a1.w += bf2f(u1.w) * m1;
        a0.x += bf2f(u2.x) * m2; a0.y += bf2f(u2.y) * m2;
        a0.z += bf2f(u2.z) * m2; a0.w += bf2f(u2.w) * m2;
        a1.x += bf2f(u3.x) * m3; a1.y += bf2f(u3.y) * m3;
        a1.z += bf2f(u3.z) * m3; a1.w += bf2f(u3.w) * m3;
    }
    for (; j < e; ++j) {
        int2 p = perm[j];
        float nm = __int_as_float(p.y);
        ushort4 u = *(const ushort4*)(H + (long)p.x * F + q * 4);
        a0.x += bf2f(u.x) * nm; a0.y += bf2f(u.y) * nm;
        a0.z += bf2f(u.z) * nm; a0.w += bf2f(u.w) * nm;
    }
    float di = dinv[node], d2 = di * di;
    ushort4 su = *(const ushort4*)(H + (long)node * F + q * 4);
    float4 o = make_float4(a0.x + a1.x + d2 * bf2f(su.x), a0.y + a1.y + d2 * bf2f(su.y),
                           a0.z + a1.z + d2 * bf2f(su.z), a0.w + a1.w + d2 * bf2f(su.w));
    *(float4*)(agg + (long)node * F + q * 4) = o;
}

// out[N,FOUT] = relu(X[N,K] @ W[K,FOUT] + bias)
// thread = (NPT=4 consecutive nodes, 4 feats), q-minor lanes (coalesced X/W/out);
// W staged in LDS; per W ds_read_b128: 16 FMAs. Block owns NPB consecutive nodes.
// BF16OUT: store ushort4 bf16. FUSE_POOL: hierarchical max-pool (2-graph LDS
// window, zero-skipping flush; direct global atomics if rel >= 2).
template<int K, int FOUT, int BLK, bool FUSE_POOL, bool BF16OUT>
__global__ __launch_bounds__(BLK)
void gemm_kernel(const float* __restrict__ X, const float* __restrict__ W,
                 const float* __restrict__ bias, void* __restrict__ out,
                 const int* __restrict__ batch, unsigned int* __restrict__ g, int N) {
    constexpr int NPT = 4;                 // nodes per thread
    constexpr int TPQ = FOUT / 4;          // feature-group slots
    constexpr int PSLOTS = BLK / TPQ;      // node-groups per block
    constexpr int NPB = PSLOTS * NPT;      // nodes per block
    __shared__ float wsm[K * FOUT];
    __shared__ unsigned int gma[FUSE_POOL ? 2 * FOUT : 1];
    __shared__ int gfirst;
    for (int i = threadIdx.x; i < K * FOUT; i += BLK) wsm[i] = W[i];
    if (FUSE_POOL) {
        if (threadIdx.x == 0) gfirst = batch[min((int)(blockIdx.x * NPB), N - 1)];
        for (int i = threadIdx.x; i < 2 * FOUT; i += BLK) gma[i] = 0u;
    }
    __syncthreads();

    int q = threadIdx.x % TPQ, p = threadIdx.x / TPQ;
    long nbase = (long)blockIdx.x * NPB + (long)p * NPT;

    float4 acc[NPT];
#pragma unroll
    for (int t = 0; t < NPT; ++t) acc[t] = make_float4(0.f, 0.f, 0.f, 0.f);

    const float* wq = wsm + q * 4;
#pragma unroll 4
    for (int i = 0; i < K / 4; ++i) {
        float4 xv[NPT];
#pragma unroll
        for (int t = 0; t < NPT; ++t) {
            long n = nbase + t; if (n >= N) n = N - 1;    // clamp (masked at store)
            xv[t] = *(const float4*)(X + n * K + i * 4);
        }
#pragma unroll
        for (int j = 0; j < 4; ++j) {
            float4 wv = *(const float4*)(wq + (i * 4 + j) * FOUT);
#pragma unroll
            for (int t = 0; t < NPT; ++t) {
                float v = ((const float*)&xv[t])[j];
                acc[t].x += v * wv.x; acc[t].y += v * wv.y;
                acc[t].z += v * wv.z; acc[t].w += v * wv.w;
            }
        }
    }

    float4 bv = *(const float4*)(bias + q * 4);
#pragma unroll
    for (int t = 0; t < NPT; ++t) {
        acc[t].x = fmaxf(acc[t].x + bv.x, 0.f);
        acc[t].y = fmaxf(acc[t].y + bv.y, 0.f);
        acc[t].z = fmaxf(acc[t].z + bv.z, 0.f);
        acc[t].w = fmaxf(acc[t].w + bv.w, 0.f);
    }

    if (!FUSE_POOL) {
        if (BF16OUT) {
            ushort* ob = (ushort*)out;
#pragma unroll
            for (int t = 0; t < NPT; ++t) {
                long n = nbase + t;
                if (n < N)
                    *(ushort4*)(ob + n * FOUT + q * 4) =
                        make_ushort4(f2bf(acc[t].x), f2bf(acc[t].y),
                                     f2bf(acc[t].z), f2bf(acc[t].w));
            }
        } else {
            float* of = (float*)out;
#pragma unroll
            for (int t = 0; t < NPT; ++t) {
                long n = nbase + t;
                if (n < N) *(float4*)(of + n * FOUT + q * 4) = acc[t];
            }
        }
        return;
    }

    // ---- hierarchical pool ----
#pragma unroll
    for (int t = 0; t < NPT; ++t) {
        long n = nbase + t;
        if (n < N) {
            unsigned int bx = __float_as_uint(acc[t].x), by = __float_as_uint(acc[t].y);
            unsigned int bz = __float_as_uint(acc[t].z), bw = __float_as_uint(acc[t].w);
            int rel = batch[n] - gfirst;
            if (rel < 2) {
                unsigned int* d = gma + rel * FOUT + q * 4;
                atomicMax(d + 0, bx); atomicMax(d + 1, by);
                atomicMax(d + 2, bz); atomicMax(d + 3, bw);
            } else {
                unsigned int* d = g + (long)batch[n] * FOUT + q * 4;
                atomicMax(d + 0, bx); atomicMax(d + 1, by);
                atomicMax(d + 2, bz); atomicMax(d + 3, bw);
            }
        }
    }
    __syncthreads();
    for (int i = threadIdx.x; i < 2 * FOUT; i += BLK) {
        unsigned int v = gma[i];
        if (v) atomicMax(&g[(long)(gfirst + i / FOUT) * FOUT + (i % FOUT)], v);
    }
}

// one block per graph: relu(g@Wfc1+bfc1) @ Wfc2 + bfc2 -> softmax
__global__ void fc_kernel(const float* __restrict__ g, const float* __restrict__ Wfc1,
                          const float* __restrict__ bfc1, const float* __restrict__ Wfc2,
                          const float* __restrict__ bfc2, float* __restrict__ out) {
    __shared__ float gs[128];
    __shared__ float red0[256], red1[256];
    int b = blockIdx.x, tid = threadIdx.x;
    if (tid < 128) gs[tid] = g[b * 128 + tid];
    __syncthreads();
    float h0 = bfc1[tid], h1 = bfc1[tid + 256];
    for (int k = 0; k < 128; ++k) {
        float gv = gs[k];
        h0 += gv * Wfc1[k * 512 + tid];
        h1 += gv * Wfc1[k * 512 + tid + 256];
    }
    h0 = fmaxf(h0, 0.f); h1 = fmaxf(h1, 0.f);
    red0[tid] = h0 * Wfc2[tid * 2 + 0] + h1 * Wfc2[(tid + 256) * 2 + 0];
    red1[tid] = h0 * Wfc2[tid * 2 + 1] + h1 * Wfc2[(tid + 256) * 2 + 1];
    __syncthreads();
    for (int s = 128; s > 0; s >>= 1) {
        if (tid < s) { red0[tid] += red0[tid + s]; red1[tid] += red1[tid + s]; }
        __syncthreads();
    }
    if (tid == 0) {
        float L0 = red0[0] + bfc2[0], L1 = red1[0] + bfc2[1];
        float m = fmaxf(L0, L1);
        float e0 = expf(L0 - m), e1 = expf(L1 - m);
        float inv = 1.f / (e0 + e1);
        out[b * 2 + 0] = e0 * inv;
        out[b * 2 + 1] = e1 * inv;
    }
}

extern "C" void kernel_launch(void* const* d_in, const int* in_sizes, int n_in,
                              void* d_out, int out_size, void* d_ws, size_t ws_size,
                              hipStream_t stream) {
    const float* x     = (const float*)d_in[0];
    const int*   ei    = (const int*)d_in[1];
    const float* ew    = (const float*)d_in[2];
    const int*   batch = (const int*)d_in[3];
    const float* W1    = (const float*)d_in[4];
    const float* b1    = (const float*)d_in[5];
    const float* W2    = (const float*)d_in[6];
    const float* b2    = (const float*)d_in[7];
    const float* W3    = (const float*)d_in[8];
    const float* b3    = (const float*)d_in[9];
    const float* Wfc1  = (const float*)d_in[10];
    const float* bfc1  = (const float*)d_in[11];
    const float* Wfc2  = (const float*)d_in[12];
    const float* bfc2  = (const float*)d_in[13];

    const int N = in_sizes[3];      // 100000
    const int E = in_sizes[2];      // 1600000
    const int* row = ei;
    const int* col = ei + E;

    char* ws = (char*)d_ws;
    float* dinv   = (float*)ws;              ws += align256((size_t)N * 4);
    unsigned long long* packed = (unsigned long long*)ws; ws += align256((size_t)N * 8);
    int*   offs   = (int*)ws;                ws += align256((size_t)(N + 1) * 4);
    int*   bsums  = (int*)ws;                ws += align256((size_t)1024 * 4);
    int2*  perm   = (int2*)ws;               ws += align256((size_t)E * 8);
    float* bufA   = (float*)ws;              ws += align256((size_t)N * 128 * 4);  // agg f32
    ushort* bufH  = (ushort*)ws;             ws += align256((size_t)N * 128 * 2);  // H bf16
    ushort* xbf   = (ushort*)ws;             ws += align256((size_t)N * 40 * 2);   // x bf16
    float* g      = (float*)ws;              ws += align256((size_t)512 * 128 * 4);
    int*   rank   = (int*)bufA;   // rank[E] (6.4MB) aliases bufA — dead before gather1

    const int B = 256;
    const int nScanBlocks = cdiv(N, SCHUNK);   // 98 for N=100000 (<= 1024)

    // --- gcn_norm + CSR build ---
    hipMemsetAsync(packed, 0, (size_t)N * 8, stream);
    deg_count_kernel<<<cdiv(E, B), B, 0, stream>>>(col, ew, packed, rank, E);
    scanA_kernel<<<nScanBlocks, B, 0, stream>>>(packed, dinv, bsums, N);
    scanB_kernel<<<1, 1024, 0, stream>>>(bsums, offs, nScanBlocks, N);
    scanC_kernel<<<nScanBlocks, B, 0, stream>>>(packed, bsums, offs, N);
    fill_kernel<<<cdiv(E, B), B, 0, stream>>>(row, col, ew, rank, dinv, offs, perm, E);
    f2bf_kernel<<<cdiv((long)N * 10, B), B, 0, stream>>>(x, xbf, N * 10);

    // --- conv1: agg = A*x (40-wide bf16), H1 = relu(agg@W1 + b1) -> bufH (bf16) ---
    // gemm1: K=40 FOUT=40 BLK=320 -> TPQ=10, 32 p-slots x 4 = 128 nodes/block
    gather_kernel<40><<<cdiv((long)N * 10, B), B, 0, stream>>>(
        offs, perm, xbf, dinv, bufA, N);
    gemm_kernel<40, 40, 320, false, true><<<cdiv(N, 128), 320, 0, stream>>>(
        bufA, W1, b1, bufH, nullptr, nullptr, N);

    // --- conv2: agg = A*H1 (40-wide bf16), H2 = relu(agg@W2 + b2) -> bufH (bf16) ---
    // gemm2: K=40 FOUT=80 BLK=320 -> TPQ=20, 16 p-slots x 4 = 64 nodes/block
    gather_kernel<40><<<cdiv((long)N * 10, B), B, 0, stream>>>(
        offs, perm, bufH, dinv, bufA, N);
    gemm_kernel<40, 80, 320, false, true><<<cdiv(N, 64), 320, 0, stream>>>(
        bufA, W2, b2, bufH, nullptr, nullptr, N);

    // --- conv3: agg = A*H2 (80-wide bf16), pool(relu(agg@W3 + b3)) -> g ---
    // gemm3: K=80 FOUT=128 BLK=256 -> TPQ=32, 8 p-slots x 4 = 32 nodes/block
    gather_kernel<80><<<cdiv((long)N * 20, B), B, 0, stream>>>(
        offs, perm, bufH, dinv, bufA, N);
    hipMemsetAsync(g, 0, (size_t)512 * 128 * 4, stream);
    gemm_kernel<80, 128, 256, true, false><<<cdiv(N, 32), 256, 0, stream>>>(
        bufA, W3, b3, nullptr, batch, (unsigned int*)g, N);

    // --- MLP + softmax ---
    fc_kernel<<<512, 256, 0, stream>>>(g, Wfc1, bfc1, Wfc2, bfc2, (float*)d_out);
}